// Round 2
// baseline (967.180 us; speedup 1.0000x reference)
//
#include <hip/hip_runtime.h>
#include <hip/hip_bf16.h>

typedef __hip_bfloat16 bf16;

static constexpr int Bn = 8;
static constexpr int C = 512;
static constexpr int S = 1024;
static constexpr int NH = 8;
static constexpr int HD = 64;
static constexpr int GROUPS = 32;
static constexpr int CPG = C / GROUPS;   // 16
#define EPSV 1e-5f

// ---------------- GroupNorm stats: one block per (b, group) ----------------
// stats[0..255] = mu, stats[256..511] = rstd, index b*32+g
__global__ __launch_bounds__(256) void gn_stats(const float* __restrict__ x,
                                                float* __restrict__ stats) {
    const int tid = threadIdx.x;
    const int bg = blockIdx.x;              // b*32+g
    const size_t base = (size_t)bg * CPG * S;  // group is contiguous in (b,c,s)
    const int N = CPG * S;  // 16384
    float sum = 0.f, sq = 0.f;
    for (int i = tid; i < N; i += 256) {
        float v = x[base + i];
        sum += v;
        sq += v * v;
    }
#pragma unroll
    for (int off = 32; off > 0; off >>= 1) {
        sum += __shfl_down(sum, off, 64);
        sq  += __shfl_down(sq,  off, 64);
    }
    __shared__ float s0[4], s1[4];
    if ((tid & 63) == 0) { s0[tid >> 6] = sum; s1[tid >> 6] = sq; }
    __syncthreads();
    if (tid == 0) {
        float a  = s0[0] + s0[1] + s0[2] + s0[3];
        float b2 = s1[0] + s1[1] + s1[2] + s1[3];
        float mu = a / (float)N;
        float var = fmaxf(b2 / (float)N - mu * mu, 0.f);
        stats[bg] = mu;
        stats[256 + bg] = rsqrtf(var + EPSV);
    }
}

// ------------- qkv GEMM with fused GroupNorm-apply on the X tile -------------
// Y[b,o,s] = sum_c W[o,c] * GN(x)[b,c,s] + bias[o];  Y is bf16 [b][1536][1024]
__global__ __launch_bounds__(256) void qkv_gemm(const float* __restrict__ W,
                                                const float* __restrict__ x,
                                                const float* __restrict__ bias,
                                                const float* __restrict__ gamma,
                                                const float* __restrict__ beta,
                                                const float* __restrict__ stats,
                                                bf16* __restrict__ Y) {
    const int K = C, O = 3 * C;
    const int b = blockIdx.z;
    const int o0 = blockIdx.y * 64;
    const int s0 = blockIdx.x * 64;
    const int tid = threadIdx.x;
    const int tx = tid & 15, ty = tid >> 4;
    __shared__ float Wt[16][68];  // [k][o], pad 4: 16B-aligned float4 rows
    __shared__ float Xt[16][64];  // [k][s]
    float acc[4][4] = {};
    const float* Xb = x + (size_t)b * K * S;
    for (int k0 = 0; k0 < K; k0 += 16) {
#pragma unroll
        for (int i = 0; i < 4; ++i) {
            int e = i * 256 + tid;
            int oo = e >> 4, kk = e & 15;
            Wt[kk][oo] = W[(size_t)(o0 + oo) * K + k0 + kk];
            int kk2 = e >> 6, ss = e & 63;
            int c = k0 + kk2, g = c >> 4;          // wave-uniform (64 lanes share c)
            float mu = stats[b * 32 + g], rstd = stats[256 + b * 32 + g];
            float v = (Xb[(size_t)c * S + s0 + ss] - mu) * rstd;
            Xt[kk2][ss] = v * gamma[c] + beta[c];
        }
        __syncthreads();
#pragma unroll
        for (int kk = 0; kk < 16; ++kk) {
            float4 xv = *reinterpret_cast<const float4*>(&Xt[kk][tx * 4]);
            float4 wv = *reinterpret_cast<const float4*>(&Wt[kk][ty * 4]);
            float xa[4] = {xv.x, xv.y, xv.z, xv.w};
            float wa[4] = {wv.x, wv.y, wv.z, wv.w};
#pragma unroll
            for (int i = 0; i < 4; ++i)
#pragma unroll
                for (int j = 0; j < 4; ++j) acc[i][j] += wa[i] * xa[j];
        }
        __syncthreads();
    }
#pragma unroll
    for (int i = 0; i < 4; ++i) {
        int o = o0 + ty * 4 + i;
        float bz = bias[o];
        size_t row = ((size_t)b * O + o) * S + s0 + tx * 4;
#pragma unroll
        for (int j = 0; j < 4; ++j)
            Y[row + j] = __float2bfloat16(acc[i][j] + bz);
    }
}

// ---------------- Flash attention: one thread per query row ----------------
// qkv layout: [b][o][s], o = three*512 + h*64 + d.  hout[b][h*64+d][s] = attn[b,h,s,d]
__global__ __launch_bounds__(256) void attn_kernel(const bf16* __restrict__ qkv,
                                                   bf16* __restrict__ hout) {
    const int b = blockIdx.z, h = blockIdx.y;
    const int t0 = blockIdx.x * 256;
    const int tid = threadIdx.x;
    const int t = t0 + tid;
    const size_t qbase = ((size_t)b * 3 * C + (size_t)h * HD) * S;
    const size_t kbase = qbase + (size_t)C * S;
    const size_t vbase = qbase + (size_t)2 * C * S;

    float q[HD];
#pragma unroll
    for (int d = 0; d < HD; ++d)
        q[d] = __bfloat162float(qkv[qbase + (size_t)d * S + t]) * 0.125f;  // 1/sqrt(D)

    float o[HD];
#pragma unroll
    for (int d = 0; d < HD; ++d) o[d] = 0.f;
    float m = -INFINITY, l = 0.f;

    __shared__ float ks[64][68];  // [key][d], pad 4: aligned b128 reads
    __shared__ float vs[64][68];

    for (int kt = 0; kt < S; kt += 64) {
        __syncthreads();
#pragma unroll
        for (int i = 0; i < 16; ++i) {
            int e = i * 256 + tid;
            int d = e >> 6, jj = e & 63;  // consecutive tid -> consecutive jj: coalesced
            ks[jj][d] = __bfloat162float(qkv[kbase + (size_t)d * S + kt + jj]);
            vs[jj][d] = __bfloat162float(qkv[vbase + (size_t)d * S + kt + jj]);
        }
        __syncthreads();
        for (int jj = 0; jj < 64; ++jj) {
            float s = 0.f;
#pragma unroll
            for (int d = 0; d < HD; ++d) s += q[d] * ks[jj][d];
            if (s > m) {
                float alpha = __expf(m - s);  // m=-inf -> alpha=0
                l *= alpha;
#pragma unroll
                for (int d = 0; d < HD; ++d) o[d] *= alpha;
                m = s;
            }
            float p = __expf(s - m);
            l += p;
#pragma unroll
            for (int d = 0; d < HD; ++d) o[d] += p * vs[jj][d];
        }
    }
    const float inv = 1.f / l;
    const size_t obase = ((size_t)b * C + (size_t)h * HD) * S + t0;
#pragma unroll
    for (int d = 0; d < HD; ++d)
        hout[obase + (size_t)d * S + tid] = __float2bfloat16(o[d] * inv);
}

// ---------------- proj GEMM + bias + residual, fp32 output ----------------
__global__ __launch_bounds__(256) void proj_gemm(const float* __restrict__ W,
                                                 const bf16* __restrict__ X,
                                                 const float* __restrict__ bias,
                                                 const float* __restrict__ resid,
                                                 float* __restrict__ Y) {
    const int K = C, O = C;
    const int b = blockIdx.z;
    const int o0 = blockIdx.y * 64;
    const int s0 = blockIdx.x * 64;
    const int tid = threadIdx.x;
    const int tx = tid & 15, ty = tid >> 4;
    __shared__ float Wt[16][68];
    __shared__ float Xt[16][64];
    float acc[4][4] = {};
    const bf16* Xb = X + (size_t)b * K * S;
    for (int k0 = 0; k0 < K; k0 += 16) {
#pragma unroll
        for (int i = 0; i < 4; ++i) {
            int e = i * 256 + tid;
            int oo = e >> 4, kk = e & 15;
            Wt[kk][oo] = W[(size_t)(o0 + oo) * K + k0 + kk];
            int kk2 = e >> 6, ss = e & 63;
            Xt[kk2][ss] = __bfloat162float(Xb[(size_t)(k0 + kk2) * S + s0 + ss]);
        }
        __syncthreads();
#pragma unroll
        for (int kk = 0; kk < 16; ++kk) {
            float4 xv = *reinterpret_cast<const float4*>(&Xt[kk][tx * 4]);
            float4 wv = *reinterpret_cast<const float4*>(&Wt[kk][ty * 4]);
            float xa[4] = {xv.x, xv.y, xv.z, xv.w};
            float wa[4] = {wv.x, wv.y, wv.z, wv.w};
#pragma unroll
            for (int i = 0; i < 4; ++i)
#pragma unroll
                for (int j = 0; j < 4; ++j) acc[i][j] += wa[i] * xa[j];
        }
        __syncthreads();
    }
#pragma unroll
    for (int i = 0; i < 4; ++i) {
        int o = o0 + ty * 4 + i;
        float bz = bias[o];
        size_t row = ((size_t)b * O + o) * S + s0 + tx * 4;
#pragma unroll
        for (int j = 0; j < 4; ++j)
            Y[row + j] = acc[i][j] + bz + resid[row + j];
    }
}

extern "C" void kernel_launch(void* const* d_in, const int* in_sizes, int n_in,
                              void* d_out, int out_size, void* d_ws, size_t ws_size,
                              hipStream_t stream) {
    const float* x      = (const float*)d_in[0];
    const float* gamma  = (const float*)d_in[1];
    const float* beta   = (const float*)d_in[2];
    const float* w_qkv  = (const float*)d_in[3];
    const float* b_qkv  = (const float*)d_in[4];
    const float* w_proj = (const float*)d_in[5];
    const float* b_proj = (const float*)d_in[6];
    float* out = (float*)d_out;

    char* ws = (char*)d_ws;
    float* stats = (float*)ws;                                  // 2 KB (512 floats)
    bf16* qkv  = (bf16*)(ws + 4096);                            // 24 MB
    bf16* hout = (bf16*)(ws + 4096 + (size_t)25165824);         // 8 MB

    gn_stats<<<Bn * GROUPS, 256, 0, stream>>>(x, stats);
    qkv_gemm<<<dim3(S / 64, (3 * C) / 64, Bn), 256, 0, stream>>>(
        w_qkv, x, b_qkv, gamma, beta, stats, qkv);
    attn_kernel<<<dim3(S / 256, NH, Bn), 256, 0, stream>>>(qkv, hout);
    proj_gemm<<<dim3(S / 64, C / 64, Bn), 256, 0, stream>>>(
        w_proj, hout, b_proj, x, out);
}

// Round 3
// 224.217 us; speedup vs baseline: 4.3136x; 4.3136x over previous
//
#include <hip/hip_runtime.h>
#include <hip/hip_bf16.h>

typedef __hip_bfloat16 bf16;
typedef unsigned short u16;
typedef __attribute__((ext_vector_type(8))) short bf16x8;
typedef __attribute__((ext_vector_type(4))) float f32x4;

static constexpr int Bn = 8;
static constexpr int C = 512;
static constexpr int S = 1024;
static constexpr int NH = 8;
static constexpr int HD = 64;
static constexpr int CPG = 16;
#define EPSV 1e-5f

__device__ __forceinline__ u16 f2bf(float f) {
    bf16 h = __float2bfloat16(f);
    return *reinterpret_cast<u16*>(&h);
}
__device__ __forceinline__ float bf2f(u16 u) {
    bf16 h = *reinterpret_cast<bf16*>(&u);
    return __bfloat162float(h);
}

// ---------------- GroupNorm stats: one block per (b, group) ----------------
__global__ __launch_bounds__(256) void gn_stats(const float* __restrict__ x,
                                                float* __restrict__ stats) {
    const int tid = threadIdx.x;
    const int bg = blockIdx.x;
    const size_t base = (size_t)bg * CPG * S;
    const int N = CPG * S;  // 16384
    float sum = 0.f, sq = 0.f;
    for (int i = tid * 4; i < N; i += 1024) {
        float4 v = *reinterpret_cast<const float4*>(&x[base + i]);
        sum += v.x + v.y + v.z + v.w;
        sq += v.x * v.x + v.y * v.y + v.z * v.z + v.w * v.w;
    }
#pragma unroll
    for (int off = 32; off > 0; off >>= 1) {
        sum += __shfl_down(sum, off, 64);
        sq  += __shfl_down(sq,  off, 64);
    }
    __shared__ float s0[4], s1[4];
    if ((tid & 63) == 0) { s0[tid >> 6] = sum; s1[tid >> 6] = sq; }
    __syncthreads();
    if (tid == 0) {
        float a  = s0[0] + s0[1] + s0[2] + s0[3];
        float b2 = s1[0] + s1[1] + s1[2] + s1[3];
        float mu = a / (float)N;
        float var = fmaxf(b2 / (float)N - mu * mu, 0.f);
        stats[bg] = mu;
        stats[256 + bg] = rsqrtf(var + EPSV);
    }
}

// ------- GN apply + transpose: x[b][c][s] fp32 -> xnt[b][s][c] bf16 -------
__global__ __launch_bounds__(256) void gn_apply_t(const float* __restrict__ x,
                                                  const float* __restrict__ gamma,
                                                  const float* __restrict__ beta,
                                                  const float* __restrict__ stats,
                                                  u16* __restrict__ xnt) {
    const int b = blockIdx.z, c0 = blockIdx.y * 64, s0 = blockIdx.x * 64;
    const int tid = threadIdx.x;
    __shared__ u16 T[64 * 72];
    const float* xb = x + ((size_t)b * C + c0) * S;
#pragma unroll
    for (int i = 0; i < 4; ++i) {
        int ch = i * 256 + tid;      // 1024 float4 chunks of the 64x64 fp32 tile
        int c = ch >> 4, seg = ch & 15;
        int cg = c0 + c;
        float mu = stats[b * 32 + (cg >> 4)];
        float rstd = stats[256 + b * 32 + (cg >> 4)];
        float ga = gamma[cg], be = beta[cg];
        float4 v = *reinterpret_cast<const float4*>(&xb[(size_t)c * S + s0 + seg * 4]);
        float vals[4] = {v.x, v.y, v.z, v.w};
#pragma unroll
        for (int j = 0; j < 4; ++j)
            T[(seg * 4 + j) * 72 + c] = f2bf((vals[j] - mu) * rstd * ga + be);
    }
    __syncthreads();
#pragma unroll
    for (int i = 0; i < 2; ++i) {
        int ch = i * 256 + tid;      // 512 16B chunks of the bf16 tile
        int r = ch >> 3, seg = ch & 7;
        uint4 val = *reinterpret_cast<const uint4*>(&T[r * 72 + seg * 8]);
        *reinterpret_cast<uint4*>(&xnt[(size_t)(b * S + s0 + r) * C + c0 + seg * 8]) = val;
    }
}

// ---------------- MFMA GEMM: Y[b,o,s] = W[o,:] . Xt[b,s,:] + bias ----------
// Xt is bf16 [b][s][512] (k-contiguous).  W fp32, converted during staging.
// MODE 0: bf16 output. MODE 1: fp32 output + residual.
template <int MODE>
__global__ __launch_bounds__(256) void mfma_gemm(const float* __restrict__ W,
                                                 const u16* __restrict__ Xt,
                                                 const float* __restrict__ bias,
                                                 const float* __restrict__ resid,
                                                 void* __restrict__ Yout, int O) {
    const int K = 512;
    const int b = blockIdx.z, o0 = blockIdx.y * 128, s0 = blockIdx.x * 128;
    const int tid = threadIdx.x;
    const int lane = tid & 63, w = tid >> 6;
    const int quad = lane >> 4, l15 = lane & 15;
    const int wr = w >> 1, wc = w & 1;
    __shared__ u16 As[128 * 40];  // [o][k], row stride 40 (80B: 2-way banks, 16B aligned)
    __shared__ u16 Bs[128 * 40];  // [s][k]
    f32x4 acc[4][4] = {};
    const u16* Xb = Xt + (size_t)(b * S + s0) * K;
    for (int k0 = 0; k0 < K; k0 += 32) {
#pragma unroll
        for (int i = 0; i < 2; ++i) {
            int ch = i * 256 + tid;  // 512 chunks: row(128) x seg(4) of 8 elements
            int r = ch >> 2, seg = ch & 3;
            const float* src = &W[(size_t)(o0 + r) * K + k0 + seg * 8];
            float4 v0 = *reinterpret_cast<const float4*>(src);
            float4 v1 = *reinterpret_cast<const float4*>(src + 4);
            u16 tmp[8] = {f2bf(v0.x), f2bf(v0.y), f2bf(v0.z), f2bf(v0.w),
                          f2bf(v1.x), f2bf(v1.y), f2bf(v1.z), f2bf(v1.w)};
            *reinterpret_cast<uint4*>(&As[r * 40 + seg * 8]) = *reinterpret_cast<uint4*>(tmp);
            uint4 bv = *reinterpret_cast<const uint4*>(&Xb[(size_t)r * K + k0 + seg * 8]);
            *reinterpret_cast<uint4*>(&Bs[r * 40 + seg * 8]) = bv;
        }
        __syncthreads();
        bf16x8 af[4], bfr[4];
#pragma unroll
        for (int mt = 0; mt < 4; ++mt)
            af[mt] = *reinterpret_cast<const bf16x8*>(&As[(wr * 64 + mt * 16 + l15) * 40 + quad * 8]);
#pragma unroll
        for (int nt = 0; nt < 4; ++nt)
            bfr[nt] = *reinterpret_cast<const bf16x8*>(&Bs[(wc * 64 + nt * 16 + l15) * 40 + quad * 8]);
#pragma unroll
        for (int mt = 0; mt < 4; ++mt)
#pragma unroll
            for (int nt = 0; nt < 4; ++nt)
                acc[mt][nt] = __builtin_amdgcn_mfma_f32_16x16x32_bf16(af[mt], bfr[nt], acc[mt][nt], 0, 0, 0);
        __syncthreads();
    }
#pragma unroll
    for (int mt = 0; mt < 4; ++mt) {
#pragma unroll
        for (int reg = 0; reg < 4; ++reg) {
            int o = o0 + wr * 64 + mt * 16 + quad * 4 + reg;
            float bz = bias[o];
#pragma unroll
            for (int nt = 0; nt < 4; ++nt) {
                int s = s0 + wc * 64 + nt * 16 + l15;
                size_t idx = (size_t)(b * O + o) * S + s;
                float v = acc[mt][nt][reg] + bz;
                if (MODE == 0) ((u16*)Yout)[idx] = f2bf(v);
                else           ((float*)Yout)[idx] = v + resid[idx];
            }
        }
    }
}

// ---------------- MFMA flash attention ----------------
// qkv bf16 [b][o][s], o = three*512 + h*64 + d.  Output hout_t bf16 [b][s][c].
__global__ __launch_bounds__(256) void attn_mfma(const u16* __restrict__ qkv,
                                                 u16* __restrict__ houtt) {
    const int b = blockIdx.z, h = blockIdx.y, q0 = blockIdx.x * 64;
    const int tid = threadIdx.x;
    const int lane = tid & 63, w = tid >> 6;
    const int quad = lane >> 4, l15 = lane & 15;
    __shared__ u16 qs[64 * 72];  // [t][d]   transposed
    __shared__ u16 ks[64 * 72];  // [key][d] transposed
    __shared__ u16 vs[64 * 72];  // [d][key] direct
    __shared__ u16 ps[64 * 72];  // [t][key] wave-private rows
    const size_t qbase = ((size_t)b * 3 * C + h * HD) * S;
    const size_t kbase = qbase + (size_t)C * S;
    const size_t vbase = qbase + (size_t)2 * C * S;

    // stage Q transposed, scaled by 1/8 (both q,k scales folded; exact in bf16)
#pragma unroll
    for (int i = 0; i < 2; ++i) {
        int ch = i * 256 + tid;
        int d = ch >> 3, seg = ch & 7;
        u16 tmp[8];
        *reinterpret_cast<uint4*>(tmp) =
            *reinterpret_cast<const uint4*>(&qkv[qbase + (size_t)d * S + q0 + seg * 8]);
#pragma unroll
        for (int j = 0; j < 8; ++j)
            qs[(seg * 8 + j) * 72 + d] = f2bf(bf2f(tmp[j]) * 0.125f);
    }
    f32x4 o_acc[4] = {};
    float m_i[4], l_i[4];
#pragma unroll
    for (int r = 0; r < 4; ++r) { m_i[r] = -INFINITY; l_i[r] = 0.f; }
    __syncthreads();

    for (int kt = 0; kt < S; kt += 64) {
#pragma unroll
        for (int i = 0; i < 2; ++i) {
            int ch = i * 256 + tid;
            int d = ch >> 3, seg = ch & 7;
            u16 tmp[8];
            *reinterpret_cast<uint4*>(tmp) =
                *reinterpret_cast<const uint4*>(&qkv[kbase + (size_t)d * S + kt + seg * 8]);
#pragma unroll
            for (int j = 0; j < 8; ++j) ks[(seg * 8 + j) * 72 + d] = tmp[j];
            *reinterpret_cast<uint4*>(&vs[d * 72 + seg * 8]) =
                *reinterpret_cast<const uint4*>(&qkv[vbase + (size_t)d * S + kt + seg * 8]);
        }
        __syncthreads();
        // S = Q K^T   (row = query quad*4+reg, col = key l15, tiles nt over keys)
        f32x4 s_acc[4] = {};
#pragma unroll
        for (int kk = 0; kk < 2; ++kk) {
            bf16x8 aq = *reinterpret_cast<const bf16x8*>(&qs[(w * 16 + l15) * 72 + kk * 32 + quad * 8]);
#pragma unroll
            for (int nt = 0; nt < 4; ++nt) {
                bf16x8 bk = *reinterpret_cast<const bf16x8*>(&ks[(nt * 16 + l15) * 72 + kk * 32 + quad * 8]);
                s_acc[nt] = __builtin_amdgcn_mfma_f32_16x16x32_bf16(aq, bk, s_acc[nt], 0, 0, 0);
            }
        }
        // online softmax per row
#pragma unroll
        for (int r = 0; r < 4; ++r) {
            float mx = fmaxf(fmaxf(s_acc[0][r], s_acc[1][r]), fmaxf(s_acc[2][r], s_acc[3][r]));
#pragma unroll
            for (int off = 1; off < 16; off <<= 1) mx = fmaxf(mx, __shfl_xor(mx, off, 64));
            float mn = fmaxf(m_i[r], mx);
            float alpha = __expf(m_i[r] - mn);
            float rs = 0.f;
#pragma unroll
            for (int nt = 0; nt < 4; ++nt) {
                float p = __expf(s_acc[nt][r] - mn);
                s_acc[nt][r] = p;
                rs += p;
            }
#pragma unroll
            for (int off = 1; off < 16; off <<= 1) rs += __shfl_xor(rs, off, 64);
            l_i[r] = l_i[r] * alpha + rs;
            m_i[r] = mn;
#pragma unroll
            for (int nt = 0; nt < 4; ++nt) o_acc[nt][r] *= alpha;
        }
        // P -> LDS (C-layout scatter; rows are wave-private, no barrier needed)
#pragma unroll
        for (int nt = 0; nt < 4; ++nt)
#pragma unroll
            for (int r = 0; r < 4; ++r)
                ps[(w * 16 + quad * 4 + r) * 72 + nt * 16 + l15] = f2bf(s_acc[nt][r]);
        // O += P V
#pragma unroll
        for (int kk = 0; kk < 2; ++kk) {
            bf16x8 ap = *reinterpret_cast<const bf16x8*>(&ps[(w * 16 + l15) * 72 + kk * 32 + quad * 8]);
#pragma unroll
            for (int nt = 0; nt < 4; ++nt) {
                bf16x8 bv = *reinterpret_cast<const bf16x8*>(&vs[(nt * 16 + l15) * 72 + kk * 32 + quad * 8]);
                o_acc[nt] = __builtin_amdgcn_mfma_f32_16x16x32_bf16(ap, bv, o_acc[nt], 0, 0, 0);
            }
        }
        __syncthreads();  // protect ks/vs before next tile's staging
    }
#pragma unroll
    for (int r = 0; r < 4; ++r) {
        float inv = 1.f / l_i[r];
        int s = q0 + w * 16 + quad * 4 + r;
#pragma unroll
        for (int nt = 0; nt < 4; ++nt) {
            int c = h * HD + nt * 16 + l15;
            houtt[(size_t)(b * S + s) * C + c] = f2bf(o_acc[nt][r] * inv);
        }
    }
}

extern "C" void kernel_launch(void* const* d_in, const int* in_sizes, int n_in,
                              void* d_out, int out_size, void* d_ws, size_t ws_size,
                              hipStream_t stream) {
    const float* x      = (const float*)d_in[0];
    const float* gamma  = (const float*)d_in[1];
    const float* beta   = (const float*)d_in[2];
    const float* w_qkv  = (const float*)d_in[3];
    const float* b_qkv  = (const float*)d_in[4];
    const float* w_proj = (const float*)d_in[5];
    const float* b_proj = (const float*)d_in[6];
    float* out = (float*)d_out;

    char* ws = (char*)d_ws;
    float* stats = (float*)ws;                             // 4 KB
    u16* xnt  = (u16*)(ws + 4096);                         // 8 MB  [b][s][c] bf16
    u16* qkvb = (u16*)(ws + 4096 + (size_t)8388608);       // 24 MB [b][1536][s] bf16
    u16* houtt = xnt;  // alias: xnt dead after qkv GEMM; attn fully rewrites it

    gn_stats<<<Bn * 32, 256, 0, stream>>>(x, stats);
    gn_apply_t<<<dim3(16, 8, Bn), 256, 0, stream>>>(x, gamma, beta, stats, xnt);
    mfma_gemm<0><<<dim3(8, 12, Bn), 256, 0, stream>>>(w_qkv, xnt, b_qkv, nullptr, qkvb, 3 * C);
    attn_mfma<<<dim3(16, NH, Bn), 256, 0, stream>>>(qkvb, houtt);
    mfma_gemm<1><<<dim3(8, 4, Bn), 256, 0, stream>>>(w_proj, houtt, b_proj, x, out, C);
}

// Round 4
// 198.226 us; speedup vs baseline: 4.8792x; 1.1311x over previous
//
#include <hip/hip_runtime.h>
#include <hip/hip_bf16.h>

typedef __hip_bfloat16 bf16;
typedef unsigned short u16;
typedef __attribute__((ext_vector_type(8))) short bf16x8;
typedef __attribute__((ext_vector_type(4))) float f32x4;

static constexpr int Bn = 8;
static constexpr int C = 512;
static constexpr int S = 1024;
static constexpr int NH = 8;
static constexpr int HD = 64;
static constexpr int CPG = 16;
#define EPSV 1e-5f

__device__ __forceinline__ u16 f2bf(float f) {
    bf16 h = __float2bfloat16(f);
    return *reinterpret_cast<u16*>(&h);
}
__device__ __forceinline__ float bf2f(u16 u) {
    bf16 h = *reinterpret_cast<bf16*>(&u);
    return __bfloat162float(h);
}

// async global->LDS, 16B per lane; LDS dest = wave-uniform base + lane*16
__device__ __forceinline__ void async_copy16(const void* g, void* l) {
    __builtin_amdgcn_global_load_lds(
        (const __attribute__((address_space(1))) void*)g,
        (__attribute__((address_space(3))) void*)l, 16, 0, 0);
}

// ---------------- GroupNorm stats: one block per (b, group) ----------------
__global__ __launch_bounds__(256) void gn_stats(const float* __restrict__ x,
                                                float* __restrict__ stats) {
    const int tid = threadIdx.x;
    const int bg = blockIdx.x;
    const size_t base = (size_t)bg * CPG * S;
    const int N = CPG * S;  // 16384
    float sum = 0.f, sq = 0.f;
    for (int i = tid * 4; i < N; i += 1024) {
        float4 v = *reinterpret_cast<const float4*>(&x[base + i]);
        sum += v.x + v.y + v.z + v.w;
        sq += v.x * v.x + v.y * v.y + v.z * v.z + v.w * v.w;
    }
#pragma unroll
    for (int off = 32; off > 0; off >>= 1) {
        sum += __shfl_down(sum, off, 64);
        sq  += __shfl_down(sq,  off, 64);
    }
    __shared__ float s0[4], s1[4];
    if ((tid & 63) == 0) { s0[tid >> 6] = sum; s1[tid >> 6] = sq; }
    __syncthreads();
    if (tid == 0) {
        float a  = s0[0] + s0[1] + s0[2] + s0[3];
        float b2 = s1[0] + s1[1] + s1[2] + s1[3];
        float mu = a / (float)N;
        float var = fmaxf(b2 / (float)N - mu * mu, 0.f);
        stats[bg] = mu;
        stats[256 + bg] = rsqrtf(var + EPSV);
    }
}

// ------- GN apply + transpose: x[b][c][s] fp32 -> xnt[b][s][c] bf16 -------
__global__ __launch_bounds__(256) void gn_apply_t(const float* __restrict__ x,
                                                  const float* __restrict__ gamma,
                                                  const float* __restrict__ beta,
                                                  const float* __restrict__ stats,
                                                  u16* __restrict__ xnt) {
    const int b = blockIdx.z, c0 = blockIdx.y * 64, s0 = blockIdx.x * 64;
    const int tid = threadIdx.x;
    __shared__ u16 T[64 * 72];
    const float* xb = x + ((size_t)b * C + c0) * S;
#pragma unroll
    for (int i = 0; i < 4; ++i) {
        int ch = i * 256 + tid;
        int c = ch >> 4, seg = ch & 15;
        int cg = c0 + c;
        float mu = stats[b * 32 + (cg >> 4)];
        float rstd = stats[256 + b * 32 + (cg >> 4)];
        float ga = gamma[cg], be = beta[cg];
        float4 v = *reinterpret_cast<const float4*>(&xb[(size_t)c * S + s0 + seg * 4]);
        float vals[4] = {v.x, v.y, v.z, v.w};
#pragma unroll
        for (int j = 0; j < 4; ++j)
            T[(seg * 4 + j) * 72 + c] = f2bf((vals[j] - mu) * rstd * ga + be);
    }
    __syncthreads();
#pragma unroll
    for (int i = 0; i < 2; ++i) {
        int ch = i * 256 + tid;
        int r = ch >> 3, seg = ch & 7;
        uint4 val = *reinterpret_cast<const uint4*>(&T[r * 72 + seg * 8]);
        *reinterpret_cast<uint4*>(&xnt[(size_t)(b * S + s0 + r) * C + c0 + seg * 8]) = val;
    }
}

// ---------------- MFMA GEMM: Y[b,o,s] = W[o,:] . Xt[b,s,:] + bias ----------
// Xt bf16 [b][s][512] k-contiguous. BK=64, XOR-swizzled unpadded LDS tiles.
// As: inline fp32->bf16 convert + ds_write_b128. Bs: global_load_lds dwordx4.
// MODE 0: bf16 output [b][o][s]. MODE 1: fp32 output + residual.
template <int MODE>
__global__ __launch_bounds__(256) void mfma_gemm(const float* __restrict__ W,
                                                 const u16* __restrict__ Xt,
                                                 const float* __restrict__ bias,
                                                 const float* __restrict__ resid,
                                                 void* __restrict__ Yout, int O) {
    const int K = 512;
    const int b = blockIdx.z, o0 = blockIdx.y * 128, s0 = blockIdx.x * 128;
    const int tid = threadIdx.x;
    const int lane = tid & 63, w = tid >> 6;
    const int quad = lane >> 4, l15 = lane & 15;
    const int wr = w >> 1, wc = w & 1;
    __shared__ u16 As[128 * 64];  // [o][k-chunk swizzled]: chunk c stored at c^(row&7)
    __shared__ u16 Bs[128 * 64];
    f32x4 acc[4][4] = {};
    const u16* Xb = Xt + (size_t)(b * S + s0) * K;
    const int bs_r = (w * 4) * 8 + (lane >> 3);      // base row for this wave's DMA
    for (int k0 = 0; k0 < K; k0 += 64) {
        // ---- stage W (fp32 -> bf16), swizzled b128 writes ----
#pragma unroll
        for (int i = 0; i < 4; ++i) {
            int ch = i * 256 + tid;
            int r = ch >> 3, c = ch & 7;
            const float* src = &W[(size_t)(o0 + r) * K + k0 + c * 8];
            float4 v0 = *reinterpret_cast<const float4*>(src);
            float4 v1 = *reinterpret_cast<const float4*>(src + 4);
            u16 tmp[8] = {f2bf(v0.x), f2bf(v0.y), f2bf(v0.z), f2bf(v0.w),
                          f2bf(v1.x), f2bf(v1.y), f2bf(v1.z), f2bf(v1.w)};
            *reinterpret_cast<uint4*>(&As[r * 64 + ((c ^ (r & 7)) << 3)]) =
                *reinterpret_cast<uint4*>(tmp);
        }
        // ---- stage X via async DMA; swizzle via per-lane global address ----
#pragma unroll
        for (int i = 0; i < 4; ++i) {
            int ci = w * 4 + i;
            int r = ci * 8 + (lane >> 3);
            int c = (lane & 7) ^ (r & 7);
            async_copy16(&Xb[(size_t)r * K + k0 + c * 8], &Bs[ci * 512]);
        }
        __syncthreads();
#pragma unroll
        for (int kk = 0; kk < 2; ++kk) {
            bf16x8 af[4], bfr[4];
#pragma unroll
            for (int mt = 0; mt < 4; ++mt) {
                int R = wr * 64 + mt * 16 + l15;
                af[mt] = *reinterpret_cast<const bf16x8*>(
                    &As[R * 64 + (((kk * 4 + quad) ^ (R & 7)) << 3)]);
            }
#pragma unroll
            for (int nt = 0; nt < 4; ++nt) {
                int R = wc * 64 + nt * 16 + l15;
                bfr[nt] = *reinterpret_cast<const bf16x8*>(
                    &Bs[R * 64 + (((kk * 4 + quad) ^ (R & 7)) << 3)]);
            }
#pragma unroll
            for (int mt = 0; mt < 4; ++mt)
#pragma unroll
                for (int nt = 0; nt < 4; ++nt)
                    acc[mt][nt] = __builtin_amdgcn_mfma_f32_16x16x32_bf16(
                        af[mt], bfr[nt], acc[mt][nt], 0, 0, 0);
        }
        __syncthreads();
    }
    (void)bs_r;
#pragma unroll
    for (int mt = 0; mt < 4; ++mt) {
#pragma unroll
        for (int reg = 0; reg < 4; ++reg) {
            int o = o0 + wr * 64 + mt * 16 + quad * 4 + reg;
            float bz = bias[o];
#pragma unroll
            for (int nt = 0; nt < 4; ++nt) {
                int s = s0 + wc * 64 + nt * 16 + l15;
                size_t idx = (size_t)(b * O + o) * S + s;
                float v = acc[mt][nt][reg] + bz;
                if (MODE == 0) ((u16*)Yout)[idx] = f2bf(v);
                else           ((float*)Yout)[idx] = v + resid[idx];
            }
        }
    }
}

// ---------------- MFMA flash attention ----------------
// qkv bf16 [b][o][s], o = three*512 + h*64 + d.  Output hout_t bf16 [b][s][c].
__global__ __launch_bounds__(256) void attn_mfma(const u16* __restrict__ qkv,
                                                 u16* __restrict__ houtt) {
    const int b = blockIdx.z, h = blockIdx.y, q0 = blockIdx.x * 64;
    const int tid = threadIdx.x;
    const int lane = tid & 63, w = tid >> 6;
    const int quad = lane >> 4, l15 = lane & 15;
    __shared__ u16 qs[64 * 72];  // [t][d], col' = d ^ 8*(row>>3)
    __shared__ u16 ks[64 * 72];  // [key][d], same swizzle
    __shared__ u16 vs[64 * 64];  // [d][key], chunk c stored at c^(d&7) (DMA layout)
    __shared__ u16 ps[64 * 72];  // [t][key], wave-private rows
    const size_t qbase = ((size_t)b * 3 * C + h * HD) * S;
    const size_t kbase = qbase + (size_t)C * S;
    const size_t vbase = qbase + (size_t)2 * C * S;

    // ---- Q stage (scaled by 1/8 = both sqrt-scales folded; exact in bf16) ----
#pragma unroll
    for (int i = 0; i < 2; ++i) {
        int ch = i * 256 + tid;
        int d = ch >> 3, seg = ch & 7;
        u16 tmp[8];
        *reinterpret_cast<uint4*>(tmp) =
            *reinterpret_cast<const uint4*>(&qkv[qbase + (size_t)d * S + q0 + seg * 8]);
        int colp = d ^ (seg << 3);
#pragma unroll
        for (int j = 0; j < 8; ++j)
            qs[(seg * 8 + j) * 72 + colp] = f2bf(bf2f(tmp[j]) * 0.125f);
    }
    // ---- prefetch K tile 0 into registers ----
    uint4 kreg[2];
#pragma unroll
    for (int i = 0; i < 2; ++i) {
        int ch = i * 256 + tid;
        int d = ch >> 3, seg = ch & 7;
        kreg[i] = *reinterpret_cast<const uint4*>(&qkv[kbase + (size_t)d * S + seg * 8]);
    }
    f32x4 o_acc[4] = {};
    float m_i[4], l_i[4];
#pragma unroll
    for (int r = 0; r < 4; ++r) { m_i[r] = -INFINITY; l_i[r] = 0.f; }

    for (int kt = 0; kt < S; kt += 64) {
        // V tile: async DMA, swizzled via global address
#pragma unroll
        for (int i = 0; i < 2; ++i) {
            int ci = w * 2 + i;
            int r = ci * 8 + (lane >> 3);
            int c = (lane & 7) ^ (r & 7);
            async_copy16(&qkv[vbase + (size_t)r * S + kt + c * 8], &vs[ci * 512]);
        }
        // K tile: registers -> LDS transposed, swizzled (conflict-minimal)
#pragma unroll
        for (int i = 0; i < 2; ++i) {
            int ch = i * 256 + tid;
            int d = ch >> 3, seg = ch & 7;
            int colp = d ^ (seg << 3);
            u16 tmp[8];
            *reinterpret_cast<uint4*>(tmp) = kreg[i];
#pragma unroll
            for (int j = 0; j < 8; ++j) ks[(seg * 8 + j) * 72 + colp] = tmp[j];
        }
        // prefetch next K tile (register loads survive the barrier un-drained)
        if (kt + 64 < S) {
#pragma unroll
            for (int i = 0; i < 2; ++i) {
                int ch = i * 256 + tid;
                int d = ch >> 3, seg = ch & 7;
                kreg[i] = *reinterpret_cast<const uint4*>(
                    &qkv[kbase + (size_t)d * S + kt + 64 + seg * 8]);
            }
        }
        __syncthreads();
        // ---- S = Q K^T ----
        f32x4 s_acc[4] = {};
        const int Rq = w * 16 + l15;
#pragma unroll
        for (int kk = 0; kk < 2; ++kk) {
            bf16x8 aq = *reinterpret_cast<const bf16x8*>(
                &qs[Rq * 72 + (((kk * 4 + quad) ^ (Rq >> 3)) << 3)]);
#pragma unroll
            for (int nt = 0; nt < 4; ++nt) {
                int Rk = nt * 16 + l15;
                bf16x8 bk = *reinterpret_cast<const bf16x8*>(
                    &ks[Rk * 72 + (((kk * 4 + quad) ^ (Rk >> 3)) << 3)]);
                s_acc[nt] = __builtin_amdgcn_mfma_f32_16x16x32_bf16(aq, bk, s_acc[nt], 0, 0, 0);
            }
        }
        // ---- online softmax per query row ----
#pragma unroll
        for (int r = 0; r < 4; ++r) {
            float mx = fmaxf(fmaxf(s_acc[0][r], s_acc[1][r]), fmaxf(s_acc[2][r], s_acc[3][r]));
#pragma unroll
            for (int off = 1; off < 16; off <<= 1) mx = fmaxf(mx, __shfl_xor(mx, off, 64));
            float mn = fmaxf(m_i[r], mx);
            float alpha = __expf(m_i[r] - mn);
            float rs = 0.f;
#pragma unroll
            for (int nt = 0; nt < 4; ++nt) {
                float p = __expf(s_acc[nt][r] - mn);
                s_acc[nt][r] = p;
                rs += p;
            }
#pragma unroll
            for (int off = 1; off < 16; off <<= 1) rs += __shfl_xor(rs, off, 64);
            l_i[r] = l_i[r] * alpha + rs;
            m_i[r] = mn;
#pragma unroll
            for (int nt = 0; nt < 4; ++nt) o_acc[nt][r] *= alpha;
        }
        // ---- P -> LDS (wave-private rows) ----
#pragma unroll
        for (int nt = 0; nt < 4; ++nt)
#pragma unroll
            for (int r = 0; r < 4; ++r)
                ps[(w * 16 + quad * 4 + r) * 72 + nt * 16 + l15] = f2bf(s_acc[nt][r]);
        // ---- O += P V ----
#pragma unroll
        for (int kk = 0; kk < 2; ++kk) {
            bf16x8 ap = *reinterpret_cast<const bf16x8*>(
                &ps[(w * 16 + l15) * 72 + kk * 32 + quad * 8]);
#pragma unroll
            for (int nt = 0; nt < 4; ++nt) {
                int Rv = nt * 16 + l15;
                bf16x8 bv = *reinterpret_cast<const bf16x8*>(
                    &vs[Rv * 64 + (((kk * 4 + quad) ^ (Rv & 7)) << 3)]);
                o_acc[nt] = __builtin_amdgcn_mfma_f32_16x16x32_bf16(ap, bv, o_acc[nt], 0, 0, 0);
            }
        }
        __syncthreads();  // ks/vs/qs safe to overwrite next iteration
    }
#pragma unroll
    for (int r = 0; r < 4; ++r) {
        float inv = 1.f / l_i[r];
        int s = q0 + w * 16 + quad * 4 + r;
#pragma unroll
        for (int nt = 0; nt < 4; ++nt) {
            int c = h * HD + nt * 16 + l15;
            houtt[(size_t)(b * S + s) * C + c] = f2bf(o_acc[nt][r] * inv);
        }
    }
}

extern "C" void kernel_launch(void* const* d_in, const int* in_sizes, int n_in,
                              void* d_out, int out_size, void* d_ws, size_t ws_size,
                              hipStream_t stream) {
    const float* x      = (const float*)d_in[0];
    const float* gamma  = (const float*)d_in[1];
    const float* beta   = (const float*)d_in[2];
    const float* w_qkv  = (const float*)d_in[3];
    const float* b_qkv  = (const float*)d_in[4];
    const float* w_proj = (const float*)d_in[5];
    const float* b_proj = (const float*)d_in[6];
    float* out = (float*)d_out;

    char* ws = (char*)d_ws;
    float* stats = (float*)ws;                             // 4 KB
    u16* xnt  = (u16*)(ws + 4096);                         // 8 MB  [b][s][c] bf16
    u16* qkvb = (u16*)(ws + 4096 + (size_t)8388608);       // 24 MB [b][1536][s] bf16
    u16* houtt = xnt;  // alias: xnt dead after qkv GEMM; attn fully rewrites it

    gn_stats<<<Bn * 32, 256, 0, stream>>>(x, stats);
    gn_apply_t<<<dim3(16, 8, Bn), 256, 0, stream>>>(x, gamma, beta, stats, xnt);
    mfma_gemm<0><<<dim3(8, 12, Bn), 256, 0, stream>>>(w_qkv, xnt, b_qkv, nullptr, qkvb, 3 * C);
    attn_mfma<<<dim3(16, NH, Bn), 256, 0, stream>>>(qkvb, houtt);
    mfma_gemm<1><<<dim3(8, 4, Bn), 256, 0, stream>>>(w_proj, houtt, b_proj, x, out, C);
}

// Round 5
// 170.534 us; speedup vs baseline: 5.6715x; 1.1624x over previous
//
#include <hip/hip_runtime.h>
#include <hip/hip_bf16.h>

typedef __hip_bfloat16 bf16;
typedef unsigned short u16;
typedef __attribute__((ext_vector_type(8))) short bf16x8;
typedef __attribute__((ext_vector_type(4))) float f32x4;

static constexpr int Bn = 8;
static constexpr int C = 512;
static constexpr int S = 1024;
static constexpr int NH = 8;
static constexpr int HD = 64;
static constexpr int CPG = 16;
#define EPSV 1e-5f

__device__ __forceinline__ u16 f2bf(float f) {
    bf16 h = __float2bfloat16(f);
    return *reinterpret_cast<u16*>(&h);
}

// async global->LDS, 16B per lane; LDS dest = wave-uniform base + lane*16
__device__ __forceinline__ void async_copy16(const void* g, void* l) {
    __builtin_amdgcn_global_load_lds(
        (const __attribute__((address_space(1))) void*)g,
        (__attribute__((address_space(3))) void*)l, 16, 0, 0);
}

// ------------- W fp32 -> bf16 (Q rows pre-scaled by 1/8, exact) -------------
__global__ __launch_bounds__(256) void wconv(const float* __restrict__ w,
                                             u16* __restrict__ out) {
    int i = (blockIdx.x * 256 + threadIdx.x) * 4;  // 1536*512 total
    float4 v = *reinterpret_cast<const float4*>(&w[i]);
    float sc = (i < 512 * 512) ? 0.125f : 1.f;     // rows o<512 are Q
    u16 t[4] = {f2bf(v.x * sc), f2bf(v.y * sc), f2bf(v.z * sc), f2bf(v.w * sc)};
    *reinterpret_cast<uint2*>(&out[i]) = *reinterpret_cast<uint2*>(t);
}

// ---------------- GroupNorm stats: one block per (b, group) ----------------
__global__ __launch_bounds__(256) void gn_stats(const float* __restrict__ x,
                                                float* __restrict__ stats) {
    const int tid = threadIdx.x;
    const int bg = blockIdx.x;
    const size_t base = (size_t)bg * CPG * S;
    const int N = CPG * S;  // 16384
    float sum = 0.f, sq = 0.f;
    for (int i = tid * 4; i < N; i += 1024) {
        float4 v = *reinterpret_cast<const float4*>(&x[base + i]);
        sum += v.x + v.y + v.z + v.w;
        sq += v.x * v.x + v.y * v.y + v.z * v.z + v.w * v.w;
    }
#pragma unroll
    for (int off = 32; off > 0; off >>= 1) {
        sum += __shfl_down(sum, off, 64);
        sq  += __shfl_down(sq,  off, 64);
    }
    __shared__ float s0[4], s1[4];
    if ((tid & 63) == 0) { s0[tid >> 6] = sum; s1[tid >> 6] = sq; }
    __syncthreads();
    if (tid == 0) {
        float a  = s0[0] + s0[1] + s0[2] + s0[3];
        float b2 = s1[0] + s1[1] + s1[2] + s1[3];
        float mu = a / (float)N;
        float var = fmaxf(b2 / (float)N - mu * mu, 0.f);
        stats[bg] = mu;
        stats[256 + bg] = rsqrtf(var + EPSV);
    }
}

// ------- GN apply + transpose: x[b][c][s] fp32 -> xnt[b][s][c] bf16 -------
__global__ __launch_bounds__(256) void gn_apply_t(const float* __restrict__ x,
                                                  const float* __restrict__ gamma,
                                                  const float* __restrict__ beta,
                                                  const float* __restrict__ stats,
                                                  u16* __restrict__ xnt) {
    const int b = blockIdx.z, c0 = blockIdx.y * 64, s0 = blockIdx.x * 64;
    const int tid = threadIdx.x;
    __shared__ u16 T[64 * 72];
    const float* xb = x + ((size_t)b * C + c0) * S;
#pragma unroll
    for (int i = 0; i < 4; ++i) {
        int ch = i * 256 + tid;
        int c = ch >> 4, seg = ch & 15;
        int cg = c0 + c;
        float mu = stats[b * 32 + (cg >> 4)];
        float rstd = stats[256 + b * 32 + (cg >> 4)];
        float ga = gamma[cg], be = beta[cg];
        float4 v = *reinterpret_cast<const float4*>(&xb[(size_t)c * S + s0 + seg * 4]);
        float vals[4] = {v.x, v.y, v.z, v.w};
#pragma unroll
        for (int j = 0; j < 4; ++j)
            T[(seg * 4 + j) * 72 + c] = f2bf((vals[j] - mu) * rstd * ga + be);
    }
    __syncthreads();
#pragma unroll
    for (int i = 0; i < 2; ++i) {
        int ch = i * 256 + tid;
        int r = ch >> 3, seg = ch & 7;
        uint4 val = *reinterpret_cast<const uint4*>(&T[r * 72 + seg * 8]);
        *reinterpret_cast<uint4*>(&xnt[(size_t)(b * S + s0 + r) * C + c0 + seg * 8]) = val;
    }
}

// ---------------- MFMA GEMM ----------------
// MODE 0 (qkv): A = pre-converted bf16 wbf via DMA; o<1024 (q,k) written
//   transposed to qkvT[b][s][1024]; o>=1024 (v) written to qkvV[b][512][S].
// MODE 1 (proj): A = fp32 W inline-converted; fp32 output + residual.
template <int MODE>
__global__ __launch_bounds__(256) void mfma_gemm(const float* __restrict__ Wf,
                                                 const u16* __restrict__ Wb,
                                                 const u16* __restrict__ Xt,
                                                 const float* __restrict__ bias,
                                                 const float* __restrict__ resid,
                                                 u16* __restrict__ qkvT,
                                                 u16* __restrict__ qkvV,
                                                 float* __restrict__ Yf) {
    const int K = 512;
    const int b = blockIdx.z, o0 = blockIdx.y * 128, s0 = blockIdx.x * 128;
    const int tid = threadIdx.x;
    const int lane = tid & 63, w = tid >> 6;
    const int quad = lane >> 4, l15 = lane & 15;
    const int wr = w >> 1, wc = w & 1;
    __shared__ u16 As[128 * 64];  // [o][k-chunk]: chunk c at slot c^(row&7)
    __shared__ u16 Bs[128 * 64];
    f32x4 acc[4][4] = {};
    const u16* Xb = Xt + (size_t)(b * S + s0) * K;
    for (int k0 = 0; k0 < K; k0 += 64) {
        if (MODE == 0) {
            // A via async DMA from bf16 weights, swizzle via global address
#pragma unroll
            for (int i = 0; i < 4; ++i) {
                int ci = w * 4 + i;
                int r = ci * 8 + (lane >> 3);
                int c = (lane & 7) ^ (r & 7);
                async_copy16(&Wb[(size_t)(o0 + r) * K + k0 + c * 8], &As[ci * 512]);
            }
        } else {
            // A: inline fp32 -> bf16 convert, swizzled b128 writes
#pragma unroll
            for (int i = 0; i < 4; ++i) {
                int ch = i * 256 + tid;
                int r = ch >> 3, c = ch & 7;
                const float* src = &Wf[(size_t)(o0 + r) * K + k0 + c * 8];
                float4 v0 = *reinterpret_cast<const float4*>(src);
                float4 v1 = *reinterpret_cast<const float4*>(src + 4);
                u16 tmp[8] = {f2bf(v0.x), f2bf(v0.y), f2bf(v0.z), f2bf(v0.w),
                              f2bf(v1.x), f2bf(v1.y), f2bf(v1.z), f2bf(v1.w)};
                *reinterpret_cast<uint4*>(&As[r * 64 + ((c ^ (r & 7)) << 3)]) =
                    *reinterpret_cast<uint4*>(tmp);
            }
        }
        // B via async DMA
#pragma unroll
        for (int i = 0; i < 4; ++i) {
            int ci = w * 4 + i;
            int r = ci * 8 + (lane >> 3);
            int c = (lane & 7) ^ (r & 7);
            async_copy16(&Xb[(size_t)r * K + k0 + c * 8], &Bs[ci * 512]);
        }
        __syncthreads();
#pragma unroll
        for (int kk = 0; kk < 2; ++kk) {
            bf16x8 af[4], bfr[4];
#pragma unroll
            for (int mt = 0; mt < 4; ++mt) {
                int R = wr * 64 + mt * 16 + l15;
                af[mt] = *reinterpret_cast<const bf16x8*>(
                    &As[R * 64 + (((kk * 4 + quad) ^ (R & 7)) << 3)]);
            }
#pragma unroll
            for (int nt = 0; nt < 4; ++nt) {
                int R = wc * 64 + nt * 16 + l15;
                bfr[nt] = *reinterpret_cast<const bf16x8*>(
                    &Bs[R * 64 + (((kk * 4 + quad) ^ (R & 7)) << 3)]);
            }
#pragma unroll
            for (int mt = 0; mt < 4; ++mt)
#pragma unroll
                for (int nt = 0; nt < 4; ++nt)
                    acc[mt][nt] = __builtin_amdgcn_mfma_f32_16x16x32_bf16(
                        af[mt], bfr[nt], acc[mt][nt], 0, 0, 0);
        }
        __syncthreads();
    }
    if (MODE == 1) {
#pragma unroll
        for (int mt = 0; mt < 4; ++mt) {
#pragma unroll
            for (int reg = 0; reg < 4; ++reg) {
                int o = o0 + wr * 64 + mt * 16 + quad * 4 + reg;
                float bz = bias[o];
#pragma unroll
                for (int nt = 0; nt < 4; ++nt) {
                    int s = s0 + wc * 64 + nt * 16 + l15;
                    size_t idx = (size_t)(b * C + o) * S + s;
                    Yf[idx] = acc[mt][nt][reg] + bz + resid[idx];
                }
            }
        }
    } else if (o0 < 1024) {
        // q,k -> transposed layout [b][s][1024]; bias scaled 1/8 for q rows
        float bsc = (o0 < 512) ? 0.125f : 1.f;
#pragma unroll
        for (int mt = 0; mt < 4; ++mt) {
            int o_b = o0 + wr * 64 + mt * 16 + quad * 4;
            float bz[4];
#pragma unroll
            for (int reg = 0; reg < 4; ++reg) bz[reg] = bias[o_b + reg] * bsc;
#pragma unroll
            for (int nt = 0; nt < 4; ++nt) {
                int s = s0 + wc * 64 + nt * 16 + l15;
                u16 t4[4];
#pragma unroll
                for (int reg = 0; reg < 4; ++reg)
                    t4[reg] = f2bf(acc[mt][nt][reg] + bz[reg]);
                *reinterpret_cast<uint2*>(&qkvT[(size_t)(b * S + s) * 1024 + o_b]) =
                    *reinterpret_cast<uint2*>(t4);
            }
        }
    } else {
        // v -> [b][v-channel][S]
#pragma unroll
        for (int mt = 0; mt < 4; ++mt) {
#pragma unroll
            for (int reg = 0; reg < 4; ++reg) {
                int o = o0 - 1024 + wr * 64 + mt * 16 + quad * 4 + reg;
                float bz = bias[o + 1024];
#pragma unroll
                for (int nt = 0; nt < 4; ++nt) {
                    int s = s0 + wc * 64 + nt * 16 + l15;
                    qkvV[(size_t)(b * 512 + o) * S + s] = f2bf(acc[mt][nt][reg] + bz);
                }
            }
        }
    }
}

// ---------------- MFMA flash attention (transposed: S^T = K Q^T) ----------
// qkvT bf16 [b][s][1024] (q:0-511, k:512-1023, d-contiguous).
// qkvV bf16 [b][512][S] ([v-channel][s]).  Output houtt bf16 [b][s][512].
__global__ __launch_bounds__(256) void attn_mfma(const u16* __restrict__ qkvT,
                                                 const u16* __restrict__ qkvV,
                                                 u16* __restrict__ houtt) {
    const int b = blockIdx.z, h = blockIdx.y, q0 = blockIdx.x * 64;
    const int tid = threadIdx.x;
    const int lane = tid & 63, w = tid >> 6;
    const int quad = lane >> 4, l15 = lane & 15;
    __shared__ u16 qs[64 * 64];  // [t][d] swizzled (DMA)
    __shared__ u16 ks[64 * 64];  // [key][d] swizzled (DMA)
    __shared__ u16 vs[64 * 64];  // [d][key] swizzled (DMA)
    __shared__ u16 ps[64 * 72];  // [t][key] packed b64 writes

    // ---- stage Q via DMA ----
    const u16* qrow = qkvT + (size_t)(b * S + q0) * 1024 + h * HD;
#pragma unroll
    for (int i = 0; i < 2; ++i) {
        int ci = w * 2 + i;
        int r = ci * 8 + (lane >> 3);
        int c = (lane & 7) ^ (r & 7);
        async_copy16(&qrow[(size_t)r * 1024 + c * 8], &qs[ci * 512]);
    }
    __syncthreads();
    // hoist Q B-frags (constant over K-loop)
    const int Rq = w * 16 + l15;
    bf16x8 qfrag[2];
#pragma unroll
    for (int kk = 0; kk < 2; ++kk)
        qfrag[kk] = *reinterpret_cast<const bf16x8*>(
            &qs[Rq * 64 + (((kk * 4 + quad) ^ (Rq & 7)) << 3)]);

    f32x4 o_acc[4] = {};
    float m_i = -INFINITY, l_i = 0.f;  // per-lane: one query (col = l15)

    const u16* krow = qkvT + (size_t)b * S * 1024 + 512 + h * HD;
    const u16* vrow = qkvV + (size_t)(b * 512 + h * HD) * S;
    for (int kt = 0; kt < S; kt += 64) {
        // ---- stage K, V via DMA (no scalar LDS writes anywhere) ----
#pragma unroll
        for (int i = 0; i < 2; ++i) {
            int ci = w * 2 + i;
            int r = ci * 8 + (lane >> 3);
            int c = (lane & 7) ^ (r & 7);
            async_copy16(&krow[(size_t)(kt + r) * 1024 + c * 8], &ks[ci * 512]);
            async_copy16(&vrow[(size_t)r * S + kt + c * 8], &vs[ci * 512]);
        }
        __syncthreads();
        // ---- S^T = K Q^T : rows = keys (4 mt tiles), cols = queries ----
        f32x4 s_acc[4] = {};
#pragma unroll
        for (int kk = 0; kk < 2; ++kk)
#pragma unroll
            for (int mt = 0; mt < 4; ++mt) {
                int Rk = mt * 16 + l15;
                bf16x8 kf = *reinterpret_cast<const bf16x8*>(
                    &ks[Rk * 64 + (((kk * 4 + quad) ^ (Rk & 7)) << 3)]);
                s_acc[mt] = __builtin_amdgcn_mfma_f32_16x16x32_bf16(
                    kf, qfrag[kk], s_acc[mt], 0, 0, 0);
            }
        // ---- online softmax: lane holds 16 keys of its query; 2 shuffles ----
        float mx = -INFINITY;
#pragma unroll
        for (int mt = 0; mt < 4; ++mt)
#pragma unroll
            for (int reg = 0; reg < 4; ++reg) mx = fmaxf(mx, s_acc[mt][reg]);
        mx = fmaxf(mx, __shfl_xor(mx, 16, 64));
        mx = fmaxf(mx, __shfl_xor(mx, 32, 64));
        float mn = fmaxf(m_i, mx);
        float alpha = __expf(m_i - mn);
        float rs = 0.f;
#pragma unroll
        for (int mt = 0; mt < 4; ++mt)
#pragma unroll
            for (int reg = 0; reg < 4; ++reg) {
                float p = __expf(s_acc[mt][reg] - mn);
                s_acc[mt][reg] = p;
                rs += p;
            }
        rs += __shfl_xor(rs, 16, 64);
        rs += __shfl_xor(rs, 32, 64);
        l_i = l_i * alpha + rs;
        m_i = mn;
#pragma unroll
        for (int mt = 0; mt < 4; ++mt)
#pragma unroll
            for (int reg = 0; reg < 4; ++reg) o_acc[mt][reg] *= alpha;
        // ---- P^T -> LDS: 4 packed b64 writes (row = this lane's query) ----
#pragma unroll
        for (int mt = 0; mt < 4; ++mt) {
            u16 t4[4];
#pragma unroll
            for (int reg = 0; reg < 4; ++reg) t4[reg] = f2bf(s_acc[mt][reg]);
            *reinterpret_cast<uint2*>(&ps[Rq * 72 + mt * 16 + quad * 4]) =
                *reinterpret_cast<uint2*>(t4);
        }
        // ---- O^T += V^T P^T : rows = d (4 mt tiles), cols = queries ----
#pragma unroll
        for (int kk = 0; kk < 2; ++kk) {
            bf16x8 pf = *reinterpret_cast<const bf16x8*>(
                &ps[Rq * 72 + kk * 32 + quad * 8]);
#pragma unroll
            for (int mt = 0; mt < 4; ++mt) {
                int Rv = mt * 16 + l15;
                bf16x8 vf = *reinterpret_cast<const bf16x8*>(
                    &vs[Rv * 64 + (((kk * 4 + quad) ^ (Rv & 7)) << 3)]);
                o_acc[mt] = __builtin_amdgcn_mfma_f32_16x16x32_bf16(
                    vf, pf, o_acc[mt], 0, 0, 0);
            }
        }
        __syncthreads();  // ks/vs reuse next tile
    }
    // ---- epilogue: O^T col = query (lane), rows d -> packed b64 stores ----
    float inv = 1.f / l_i;
    u16* orow = houtt + (size_t)(b * S + q0 + w * 16 + l15) * 512 + h * HD;
#pragma unroll
    for (int mt = 0; mt < 4; ++mt) {
        u16 t4[4];
#pragma unroll
        for (int reg = 0; reg < 4; ++reg) t4[reg] = f2bf(o_acc[mt][reg] * inv);
        *reinterpret_cast<uint2*>(&orow[mt * 16 + quad * 4]) =
            *reinterpret_cast<uint2*>(t4);
    }
}

extern "C" void kernel_launch(void* const* d_in, const int* in_sizes, int n_in,
                              void* d_out, int out_size, void* d_ws, size_t ws_size,
                              hipStream_t stream) {
    const float* x      = (const float*)d_in[0];
    const float* gamma  = (const float*)d_in[1];
    const float* beta   = (const float*)d_in[2];
    const float* w_qkv  = (const float*)d_in[3];
    const float* b_qkv  = (const float*)d_in[4];
    const float* w_proj = (const float*)d_in[5];
    const float* b_proj = (const float*)d_in[6];
    float* out = (float*)d_out;

    char* ws = (char*)d_ws;
    float* stats = (float*)ws;                                   // 4 KB
    u16* wbf   = (u16*)(ws + 4096);                              // 1.5 MB bf16 w_qkv
    u16* xnt   = (u16*)(ws + 4096 + 1572864);                    // 8 MB [b][s][512]
    u16* qkvT  = (u16*)(ws + 4096 + 1572864 + 8388608);          // 16 MB [b][s][1024]
    u16* qkvV  = (u16*)(ws + 4096 + 1572864 + 8388608 + 16777216); // 8 MB [b][512][S]
    u16* houtt = xnt;  // alias: xnt dead after qkv GEMM; attn fully rewrites it

    wconv<<<768, 256, 0, stream>>>(w_qkv, wbf);
    gn_stats<<<Bn * 32, 256, 0, stream>>>(x, stats);
    gn_apply_t<<<dim3(16, 8, Bn), 256, 0, stream>>>(x, gamma, beta, stats, xnt);
    mfma_gemm<0><<<dim3(8, 12, Bn), 256, 0, stream>>>(
        nullptr, wbf, xnt, b_qkv, nullptr, qkvT, qkvV, nullptr);
    attn_mfma<<<dim3(16, NH, Bn), 256, 0, stream>>>(qkvT, qkvV, houtt);
    mfma_gemm<1><<<dim3(8, 4, Bn), 256, 0, stream>>>(
        w_proj, nullptr, houtt, b_proj, x, nullptr, nullptr, out);
}